// Round 3
// baseline (90.595 us; speedup 1.0000x reference)
//
#include <hip/hip_runtime.h>

#define BB 4096
#define FF 39
#define DD 128
#define FIELD_DIM 10000
#define NXCD 8

// F-major item order + per-XCD contiguous chunks (idx tables L2-resident).
// Each 32-lane group handles TWO consecutive items (same f, b and b+1) to
// double the number of independent gathers in flight per wave.
__global__ __launch_bounds__(256) void mixq_embed(
    const int* __restrict__ x,
    const float* __restrict__ arch_prob,
    const float* __restrict__ cb00, const int* __restrict__ i00,
    const float* __restrict__ cb10, const int* __restrict__ i10,
    const float* __restrict__ cb11, const int* __restrict__ i11,
    const float* __restrict__ cb12, const int* __restrict__ i12,
    const float* __restrict__ cb20, const int* __restrict__ i20,
    const float* __restrict__ cb21, const int* __restrict__ i21,
    const float* __restrict__ cb22, const int* __restrict__ i22,
    float* __restrict__ out)
{
    // Bijective XCD chunking (grid = 9984, %8 == 0).
    const int nwg  = gridDim.x;
    const int cpx  = nwg >> 3;
    const int orig = blockIdx.x;
    const int wgid = (orig & (NXCD - 1)) * cpx + (orig >> 3);

    const int gid  = (wgid * 256 + (int)threadIdx.x) >> 5;  // 32-lane group id
    const int lane = threadIdx.x & 31;
    const int d0   = lane << 2;

    const int it0 = gid << 1;              // f-major: item = f*4096 + b, b even
    const int f   = it0 >> 12;
    const int b0  = it0 & (BB - 1);

    const int xg0 = x[b0 * FF + f] + f * FIELD_DIM;
    const int xg1 = x[(b0 + 1) * FF + f] + f * FIELD_DIM;

    const float* ap = arch_prob + f * 9;

    // Stage 1: all 14 row indices (independent loads, fill the queue).
    int k2 = d0 >> 6;          // k for M=2 (plen=64)
    int k4 = d0 >> 5;          // k for M=4 (plen=32)

    int r0_00 = i00[xg0];
    int r1_00 = i00[xg1];
    int r0_10 = i10[xg0];
    int r1_10 = i10[xg1];
    int r0_11 = i11[(size_t)xg0 * 2 + k2];
    int r1_11 = i11[(size_t)xg1 * 2 + k2];
    int r0_12 = i12[(size_t)xg0 * 4 + k4];
    int r1_12 = i12[(size_t)xg1 * 4 + k4];
    int r0_20 = i20[xg0];
    int r1_20 = i20[xg1];
    int r0_21 = i21[(size_t)xg0 * 2 + k2];
    int r1_21 = i21[(size_t)xg1 * 2 + k2];
    int r0_22 = i22[(size_t)xg0 * 4 + k4];
    int r1_22 = i22[(size_t)xg1 * 4 + k4];

    float4 acc0 = make_float4(0.f, 0.f, 0.f, 0.f);
    float4 acc1 = make_float4(0.f, 0.f, 0.f, 0.f);

#define GATHER_FMA(cb, r0, r1, col)                                           \
    do {                                                                      \
        float4 v0 = *reinterpret_cast<const float4*>((cb) + (size_t)(r0) * DD + d0); \
        float4 v1 = *reinterpret_cast<const float4*>((cb) + (size_t)(r1) * DD + d0); \
        float s = ap[col];                                                    \
        acc0.x += s * v0.x; acc0.y += s * v0.y;                               \
        acc0.z += s * v0.z; acc0.w += s * v0.w;                               \
        acc1.x += s * v1.x; acc1.y += s * v1.y;                               \
        acc1.z += s * v1.z; acc1.w += s * v1.w;                               \
    } while (0)

    GATHER_FMA(cb00, r0_00, r1_00, 0);
    GATHER_FMA(cb10, r0_10, r1_10, 3);
    GATHER_FMA(cb11, r0_11, r1_11, 4);
    GATHER_FMA(cb12, r0_12, r1_12, 5);
    GATHER_FMA(cb20, r0_20, r1_20, 6);
    GATHER_FMA(cb21, r0_21, r1_21, 7);
    GATHER_FMA(cb22, r0_22, r1_22, 8);
#undef GATHER_FMA

    float* dst0 = out + ((size_t)b0 * FF + f) * DD + d0;
    float* dst1 = dst0 + (size_t)FF * DD;
    __builtin_nontemporal_store(acc0.x, dst0 + 0);
    __builtin_nontemporal_store(acc0.y, dst0 + 1);
    __builtin_nontemporal_store(acc0.z, dst0 + 2);
    __builtin_nontemporal_store(acc0.w, dst0 + 3);
    __builtin_nontemporal_store(acc1.x, dst1 + 0);
    __builtin_nontemporal_store(acc1.y, dst1 + 1);
    __builtin_nontemporal_store(acc1.z, dst1 + 2);
    __builtin_nontemporal_store(acc1.w, dst1 + 3);
}

extern "C" void kernel_launch(void* const* d_in, const int* in_sizes, int n_in,
                              void* d_out, int out_size, void* d_ws, size_t ws_size,
                              hipStream_t stream) {
    const int*   x  = (const int*)d_in[0];
    const float* ap = (const float*)d_in[1];
    const float* cb00 = (const float*)d_in[2];
    const int*   i00  = (const int*)d_in[3];
    const float* cb10 = (const float*)d_in[4];
    const int*   i10  = (const int*)d_in[5];
    const float* cb11 = (const float*)d_in[6];
    const int*   i11  = (const int*)d_in[7];
    const float* cb12 = (const float*)d_in[8];
    const int*   i12  = (const int*)d_in[9];
    const float* cb20 = (const float*)d_in[10];
    const int*   i20  = (const int*)d_in[11];
    const float* cb21 = (const float*)d_in[12];
    const int*   i21  = (const int*)d_in[13];
    const float* cb22 = (const float*)d_in[14];
    const int*   i22  = (const int*)d_in[15];
    float* out = (float*)d_out;

    // 2 items per 32-lane group: B*F/2 groups * 32 lanes / 256 = 9984 blocks.
    const long long total_threads = (long long)BB * FF * 16;
    const int threads = 256;
    const int blocks = (int)((total_threads + threads - 1) / threads);

    mixq_embed<<<blocks, threads, 0, stream>>>(
        x, ap, cb00, i00, cb10, i10, cb11, i11, cb12, i12,
        cb20, i20, cb21, i21, cb22, i22, out);
}

// Round 4
// 88.062 us; speedup vs baseline: 1.0288x; 1.0288x over previous
//
#include <hip/hip_runtime.h>

#define BB 4096
#define FF 39
#define DD 128
#define FIELD_DIM 10000

// d-HALF split across XCD groups: XCDs 0-3 compute d in [0,64) for all items,
// XCDs 4-7 compute d in [64,128). Each XCD's L2 then only ever sees HALF of
// each codebook row (and one k-part for M=2, two for M=4), shrinking the
// per-XCD random-gather pool from ~7 MB to ~3.5 MB of distinct lines.
// Within each half-group, items are f-major and chunked contiguously per XCD
// so idx-table slices stay L2-resident (R1's win, retained).
// 32-lane group = 2 items x 16 lanes; each lane owns a float4 of its d-half.
__global__ __launch_bounds__(256) void mixq_embed(
    const int* __restrict__ x,
    const float* __restrict__ arch_prob,
    const float* __restrict__ cb00, const int* __restrict__ i00,
    const float* __restrict__ cb10, const int* __restrict__ i10,
    const float* __restrict__ cb11, const int* __restrict__ i11,
    const float* __restrict__ cb12, const int* __restrict__ i12,
    const float* __restrict__ cb20, const int* __restrict__ i20,
    const float* __restrict__ cb21, const int* __restrict__ i21,
    const float* __restrict__ cb22, const int* __restrict__ i22,
    float* __restrict__ out)
{
    const int nwg  = gridDim.x;              // 19968
    const int perx = nwg >> 3;               // 2496 blocks per XCD
    const int blk  = blockIdx.x;
    const int xcd  = blk & 7;                // assumed HW round-robin mapping
    const int h    = xcd >> 2;               // d-half: 0 -> [0,64), 1 -> [64,128)
    const int wh   = (xcd & 3) * perx + (blk >> 3);  // block seq within half

    const int t   = (int)threadIdx.x;
    const int sub = (t >> 4) & 1;            // which of the 2 items in the group
    const int li  = t & 15;                  // lane within item (16 lanes)
    const int ii  = wh * 16 + ((t >> 5) << 1) + sub; // f-major item id
    const int f   = ii >> 12;                // / 4096
    const int bb  = ii & (BB - 1);           // % 4096
    const int d0  = (h << 6) + (li << 2);    // this lane's d offset

    const int xg = x[bb * FF + f] + f * FIELD_DIM;
    const float* ap = arch_prob + f * 9;

    const int k4 = (h << 1) + (li >> 3);     // d0 >> 5, for M=4

    // All 7 row indices up front (independent loads).
    int r00 = i00[xg];
    int r10 = i10[xg];
    int r11 = i11[(size_t)xg * 2 + h];
    int r12 = i12[(size_t)xg * 4 + k4];
    int r20 = i20[xg];
    int r21 = i21[(size_t)xg * 2 + h];
    int r22 = i22[(size_t)xg * 4 + k4];

    float4 acc = make_float4(0.f, 0.f, 0.f, 0.f);

#define GATHER_FMA(cb, r, col)                                                \
    do {                                                                      \
        float4 v = *reinterpret_cast<const float4*>((cb) + (size_t)(r) * DD + d0); \
        float s = ap[col];                                                    \
        acc.x += s * v.x; acc.y += s * v.y;                                   \
        acc.z += s * v.z; acc.w += s * v.w;                                   \
    } while (0)

    // Same pair order as the reference -> identical accumulation order.
    GATHER_FMA(cb00, r00, 0);
    GATHER_FMA(cb10, r10, 3);
    GATHER_FMA(cb11, r11, 4);
    GATHER_FMA(cb12, r12, 5);
    GATHER_FMA(cb20, r20, 6);
    GATHER_FMA(cb21, r21, 7);
    GATHER_FMA(cb22, r22, 8);
#undef GATHER_FMA

    float* dst = out + ((size_t)bb * FF + f) * DD + d0;
    __builtin_nontemporal_store(acc.x, dst + 0);
    __builtin_nontemporal_store(acc.y, dst + 1);
    __builtin_nontemporal_store(acc.z, dst + 2);
    __builtin_nontemporal_store(acc.w, dst + 3);
}

extern "C" void kernel_launch(void* const* d_in, const int* in_sizes, int n_in,
                              void* d_out, int out_size, void* d_ws, size_t ws_size,
                              hipStream_t stream) {
    const int*   x  = (const int*)d_in[0];
    const float* ap = (const float*)d_in[1];
    const float* cb00 = (const float*)d_in[2];
    const int*   i00  = (const int*)d_in[3];
    const float* cb10 = (const float*)d_in[4];
    const int*   i10  = (const int*)d_in[5];
    const float* cb11 = (const float*)d_in[6];
    const int*   i11  = (const int*)d_in[7];
    const float* cb12 = (const float*)d_in[8];
    const int*   i12  = (const int*)d_in[9];
    const float* cb20 = (const float*)d_in[10];
    const int*   i20  = (const int*)d_in[11];
    const float* cb21 = (const float*)d_in[12];
    const int*   i21  = (const int*)d_in[13];
    const float* cb22 = (const float*)d_in[14];
    const int*   i22  = (const int*)d_in[15];
    float* out = (float*)d_out;

    // items * 2 halves * 16 lanes = B*F*32 threads; 256/block -> 19968 blocks.
    const long long total_threads = (long long)BB * FF * 32;
    const int threads = 256;
    const int blocks = (int)((total_threads + threads - 1) / threads);

    mixq_embed<<<blocks, threads, 0, stream>>>(
        x, ap, cb00, i00, cb10, i10, cb11, i11, cb12, i12,
        cb20, i20, cb21, i21, cb22, i22, out);
}